// Round 4
// baseline (1279.283 us; speedup 1.0000x reference)
//
#include <hip/hip_runtime.h>
#include <hip/hip_bf16.h>
#include <math.h>

// Problem dims
#define CC 128          // C
#define DI 256          // D_INNER
#define SSEQ 256        // B*N sequences
#define ROWS 65536      // SSEQ*TT

typedef __hip_bfloat16 bf16;
__device__ __forceinline__ float to_f(float v) { return v; }
__device__ __forceinline__ float to_f(bf16 v)  { return __bfloat162float(v); }
__device__ __forceinline__ bf16  f2b(float v)  { return __float2bfloat16(v); }

__device__ __forceinline__ float wave_sum(float v) {
    #pragma unroll
    for (int o = 1; o < 64; o <<= 1) v += __shfl_xor(v, o, 64);
    return v;
}
__device__ __forceinline__ float silu_f(float x) { return x / (1.f + __expf(-x)); }
__device__ __forceinline__ float gelu_f(float x) { return 0.5f * x * (1.f + erff(x * 0.70710678118654752f)); }

// ---------------- LN1: x (B,T,N,C) fp32 -> bf16 rows in (s,t) order, s = b*64+n ----------------
__global__ __launch_bounds__(256) void ln1_kernel(const float* __restrict__ x,
                                                  const float* __restrict__ g,
                                                  const float* __restrict__ b,
                                                  bf16* __restrict__ out) {
    int wave = threadIdx.x >> 6, lane = threadIdx.x & 63;
    int r = blockIdx.x * 4 + wave;
    int s = r >> 8, t = r & 255;
    int bb = s >> 6, n = s & 63;
    size_t xbase = (((size_t)(bb * 256 + t)) * 64 + n) * CC;
    float v0 = x[xbase + lane], v1 = x[xbase + lane + 64];
    float s1 = wave_sum(v0 + v1);
    float s2 = wave_sum(v0 * v0 + v1 * v1);
    float m = s1 * (1.f / 128.f);
    float var = s2 * (1.f / 128.f) - m * m;
    float rstd = rsqrtf(var + 1e-5f);
    size_t ob = (size_t)r * CC;
    out[ob + lane]      = f2b((v0 - m) * rstd * g[lane]      + b[lane]);
    out[ob + lane + 64] = f2b((v1 - m) * rstd * g[lane + 64] + b[lane + 64]);
}

// ---------------- LN3: fp32 row-major in -> bf16 out ----------------
__global__ __launch_bounds__(256) void ln3_kernel(const float* __restrict__ in,
                                                  const float* __restrict__ g,
                                                  const float* __restrict__ b,
                                                  bf16* __restrict__ out) {
    int wave = threadIdx.x >> 6, lane = threadIdx.x & 63;
    int r = blockIdx.x * 4 + wave;
    size_t ib = (size_t)r * CC;
    float v0 = in[ib + lane], v1 = in[ib + lane + 64];
    float s1 = wave_sum(v0 + v1);
    float s2 = wave_sum(v0 * v0 + v1 * v1);
    float m = s1 * (1.f / 128.f);
    float var = s2 * (1.f / 128.f) - m * m;
    float rstd = rsqrtf(var + 1e-5f);
    out[ib + lane]      = f2b((v0 - m) * rstd * g[lane]      + b[lane]);
    out[ib + lane + 64] = f2b((v1 - m) * rstd * g[lane + 64] + b[lane + 64]);
}

// ---------------- Generic tiled GEMM (fp32 acc): C = A @ op(B) ----------------
// BTR=true: B is [N,K] (x @ W.T). BTR=false: B is [K,N].
// EPI: 0 = store, 1 = +bias,gelu,store, 2 = +bias, add into C.
template <typename TA, typename TB, typename TC, bool BTR, int EPI>
__global__ __launch_bounds__(256) void gemm_kernel(const TA* __restrict__ A, int lda,
                                                   const TB* __restrict__ B,
                                                   const float* __restrict__ bias,
                                                   TC* __restrict__ C, int ldc,
                                                   int N, int K) {
    __shared__ float As[16][65];
    __shared__ float Bs[16][65];
    int tid = threadIdx.x;
    int m0 = blockIdx.x * 64;
    int n0 = blockIdx.y * 64;
    int tx = tid & 15, ty = tid >> 4;
    float acc[4][4] = {};
    for (int k0 = 0; k0 < K; k0 += 16) {
        #pragma unroll
        for (int r = 0; r < 4; r++) {
            int idx = tid + r * 256;
            int m = idx >> 4, k = idx & 15;
            As[k][m] = to_f(A[(size_t)(m0 + m) * lda + k0 + k]);
        }
        if (BTR) {
            #pragma unroll
            for (int r = 0; r < 4; r++) {
                int idx = tid + r * 256;
                int n = idx >> 4, k = idx & 15;
                float v = 0.f;
                if (n0 + n < N) v = to_f(B[(size_t)(n0 + n) * K + k0 + k]);
                Bs[k][n] = v;
            }
        } else {
            #pragma unroll
            for (int r = 0; r < 4; r++) {
                int k = r * 4 + (tid >> 6);
                int n = tid & 63;
                float v = 0.f;
                if (n0 + n < N) v = to_f(B[(size_t)(k0 + k) * N + n0 + n]);
                Bs[k][n] = v;
            }
        }
        __syncthreads();
        #pragma unroll
        for (int k = 0; k < 16; k++) {
            float a[4], bv[4];
            #pragma unroll
            for (int i = 0; i < 4; i++) a[i] = As[k][ty * 4 + i];
            #pragma unroll
            for (int j = 0; j < 4; j++) bv[j] = Bs[k][tx * 4 + j];
            #pragma unroll
            for (int i = 0; i < 4; i++)
                #pragma unroll
                for (int j = 0; j < 4; j++) acc[i][j] += a[i] * bv[j];
        }
        __syncthreads();
    }
    #pragma unroll
    for (int i = 0; i < 4; i++) {
        int row = m0 + ty * 4 + i;
        #pragma unroll
        for (int j = 0; j < 4; j++) {
            int col = n0 + tx * 4 + j;
            if (col < N) {
                float v = acc[i][j];
                if (EPI >= 1) v += bias[col];
                if (EPI == 1) v = gelu_f(v);
                size_t o = (size_t)row * ldc + col;
                if (EPI == 2) C[o] = (TC)(to_f(C[o]) + v);
                else {
                    float r2 = v;
                    C[o] = sizeof(TC) == 2 ? (TC)f2b(r2) : (TC)r2;
                }
            }
        }
    }
}

// ---------------- xdbl GEMM with fused causal conv + SiLU A-staging ----------------
// A[m][d] = silu(conv_b[d] + sum_j w[d][j] * xc(s, src(t-3+j), d)),  m = s*256+t (scan domain)
// DIR=0 fwd (src=tj), DIR=1 bwd (src=255-tj). B = Wx [40][256] fp32. C = [ROWS][40] bf16.
template <int DIR>
__global__ __launch_bounds__(256) void gemm_conv_kernel(const bf16* __restrict__ xz,
                                                        const float* __restrict__ cw,
                                                        const float* __restrict__ cb,
                                                        const float* __restrict__ B,
                                                        bf16* __restrict__ C) {
    __shared__ float As[16][65];
    __shared__ float Bs[16][65];
    int tid = threadIdx.x;
    int m0 = blockIdx.x * 64;
    int tx = tid & 15, ty = tid >> 4;
    float acc[4][4] = {};
    for (int k0 = 0; k0 < 256; k0 += 16) {
        #pragma unroll
        for (int r = 0; r < 4; r++) {
            int idx = tid + r * 256;
            int m = idx >> 4, kk = idx & 15;
            int row = m0 + m;
            int t = row & 255, s = row >> 8;
            int d = k0 + kk;
            float a = cb[d];
            #pragma unroll
            for (int j = 0; j < 4; j++) {
                int tj = t - 3 + j;
                if (tj >= 0) {
                    int src = DIR ? (255 - tj) : tj;
                    a += cw[d * 4 + j] * to_f(xz[(size_t)(s * 256 + src) * 512 + d]);
                }
            }
            As[kk][m] = silu_f(a);
        }
        #pragma unroll
        for (int r = 0; r < 4; r++) {
            int idx = tid + r * 256;
            int n = idx >> 4, kk = idx & 15;
            Bs[kk][n] = (n < 40) ? B[(size_t)n * 256 + k0 + kk] : 0.f;
        }
        __syncthreads();
        #pragma unroll
        for (int k = 0; k < 16; k++) {
            float a[4], bv[4];
            #pragma unroll
            for (int i = 0; i < 4; i++) a[i] = As[k][ty * 4 + i];
            #pragma unroll
            for (int j = 0; j < 4; j++) bv[j] = Bs[k][tx * 4 + j];
            #pragma unroll
            for (int i = 0; i < 4; i++)
                #pragma unroll
                for (int j = 0; j < 4; j++) acc[i][j] += a[i] * bv[j];
        }
        __syncthreads();
    }
    #pragma unroll
    for (int i = 0; i < 4; i++) {
        int row = m0 + ty * 4 + i;
        #pragma unroll
        for (int j = 0; j < 4; j++) {
            int col = tx * 4 + j;
            if (col < 40) C[(size_t)row * 40 + col] = f2b(acc[i][j]);
        }
    }
}

// ---------------- Dual selective scan ----------------
// One block per (sequence, d-quarter); 64 threads, d = q*64+tid.
// Phase A: backward scan (rolling conv from xc), ungated y_b -> LDS at original time.
// Phase B: forward scan, gated (y_f+y_b)*silu(z) written IN PLACE into z-columns of xz.
__global__ __launch_bounds__(64) void scan_dual_kernel(bf16* __restrict__ xz,
        const bf16* __restrict__ xdbl_f, const bf16* __restrict__ xdbl_b,
        const float* __restrict__ cw_f, const float* __restrict__ cb_f,
        const float* __restrict__ Wdt_f, const float* __restrict__ bdt_f,
        const float* __restrict__ Alog_f, const float* __restrict__ D_f,
        const float* __restrict__ cw_b, const float* __restrict__ cb_b,
        const float* __restrict__ Wdt_b, const float* __restrict__ bdt_b,
        const float* __restrict__ Alog_b, const float* __restrict__ D_b) {
    __shared__ bf16 ybuf[256 * 64];   // y_b (ungated) indexed by ORIGINAL time
    __shared__ float sm[40];
    int tid = threadIdx.x;
    int s = blockIdx.x >> 2, q = blockIdx.x & 3;
    int d = q * 64 + tid;

    // ---- Phase A: backward ----
    {
        float A[16], wdt[8];
        #pragma unroll
        for (int n = 0; n < 16; n++) A[n] = -__expf(Alog_b[d * 16 + n]);
        #pragma unroll
        for (int r = 0; r < 8; r++) wdt[r] = Wdt_b[d * 8 + r];
        float bd = bdt_b[d], Dd = D_b[d];
        float c0 = cw_b[d * 4], c1 = cw_b[d * 4 + 1], c2 = cw_b[d * 4 + 2], c3 = cw_b[d * 4 + 3];
        float cb = cb_b[d];
        float h[16];
        #pragma unroll
        for (int n = 0; n < 16; n++) h[n] = 0.f;
        float w0 = 0.f, w1 = 0.f, w2 = 0.f, w3 = 0.f;
        for (int t = 0; t < 256; t++) {
            int orig = 255 - t;
            float xc = to_f(xz[(size_t)(s * 256 + orig) * 512 + d]);
            __syncthreads();
            if (tid < 40) sm[tid] = to_f(xdbl_b[(size_t)(s * 256 + t) * 40 + tid]);
            __syncthreads();
            w0 = w1; w1 = w2; w2 = w3; w3 = xc;
            float u = silu_f(cb + c0 * w0 + c1 * w1 + c2 * w2 + c3 * w3);
            float dtr = bd;
            #pragma unroll
            for (int r = 0; r < 8; r++) dtr += sm[r] * wdt[r];
            float dt = (dtr > 20.f) ? dtr : log1pf(__expf(dtr));
            float du = dt * u, y = 0.f;
            #pragma unroll
            for (int n = 0; n < 16; n++) {
                float dA = __expf(dt * A[n]);
                h[n] = dA * h[n] + du * sm[8 + n];
                y += h[n] * sm[24 + n];
            }
            y += u * Dd;
            ybuf[orig * 64 + tid] = f2b(y);
        }
    }
    __syncthreads();
    // ---- Phase B: forward + gate, write into z columns ----
    {
        float A[16], wdt[8];
        #pragma unroll
        for (int n = 0; n < 16; n++) A[n] = -__expf(Alog_f[d * 16 + n]);
        #pragma unroll
        for (int r = 0; r < 8; r++) wdt[r] = Wdt_f[d * 8 + r];
        float bd = bdt_f[d], Dd = D_f[d];
        float c0 = cw_f[d * 4], c1 = cw_f[d * 4 + 1], c2 = cw_f[d * 4 + 2], c3 = cw_f[d * 4 + 3];
        float cb = cb_f[d];
        float h[16];
        #pragma unroll
        for (int n = 0; n < 16; n++) h[n] = 0.f;
        float w0 = 0.f, w1 = 0.f, w2 = 0.f, w3 = 0.f;
        for (int t = 0; t < 256; t++) {
            float xc = to_f(xz[(size_t)(s * 256 + t) * 512 + d]);
            __syncthreads();
            if (tid < 40) sm[tid] = to_f(xdbl_f[(size_t)(s * 256 + t) * 40 + tid]);
            __syncthreads();
            w0 = w1; w1 = w2; w2 = w3; w3 = xc;
            float u = silu_f(cb + c0 * w0 + c1 * w1 + c2 * w2 + c3 * w3);
            float dtr = bd;
            #pragma unroll
            for (int r = 0; r < 8; r++) dtr += sm[r] * wdt[r];
            float dt = (dtr > 20.f) ? dtr : log1pf(__expf(dtr));
            float du = dt * u, y = 0.f;
            #pragma unroll
            for (int n = 0; n < 16; n++) {
                float dA = __expf(dt * A[n]);
                h[n] = dA * h[n] + du * sm[8 + n];
                y += h[n] * sm[24 + n];
            }
            y += u * Dd;
            float yb = to_f(ybuf[t * 64 + tid]);
            size_t za = (size_t)(s * 256 + t) * 512 + 256 + d;
            float z = to_f(xz[za]);
            xz[za] = f2b((y + yb) * silu_f(z));
        }
    }
}

// ---------------- W_out GEMM with fused LN2 + residual epilogue ----------------
// A = gated sum in z-columns of xz (bf16, lda 512, +256). B = W_out [128][256] fp32.
// Tile 64 rows x 128 cols (full N): row LN stats via 32-lane shuffle reduce.
__global__ __launch_bounds__(256) void gemm_ln2res_kernel(const bf16* __restrict__ xz,
                                                          const float* __restrict__ Wout,
                                                          const float* __restrict__ g,
                                                          const float* __restrict__ b,
                                                          const float* __restrict__ x,
                                                          float* __restrict__ out) {
    __shared__ float As[16][65];
    __shared__ float Bs[16][129];
    int tid = threadIdx.x;
    int m0 = blockIdx.x * 64;
    int tx = tid & 31, ty = tid >> 5;   // tx: 4 cols each (128), ty: 8 rows each (64)
    float acc[8][4] = {};
    for (int k0 = 0; k0 < 256; k0 += 16) {
        #pragma unroll
        for (int r = 0; r < 4; r++) {
            int idx = tid + r * 256;
            int m = idx >> 4, kk = idx & 15;
            As[kk][m] = to_f(xz[(size_t)(m0 + m) * 512 + 256 + k0 + kk]);
        }
        #pragma unroll
        for (int r = 0; r < 8; r++) {
            int idx = tid + r * 256;
            int n = idx >> 4, kk = idx & 15;
            Bs[kk][n] = Wout[(size_t)n * 256 + k0 + kk];
        }
        __syncthreads();
        #pragma unroll
        for (int k = 0; k < 16; k++) {
            float a[8], bv[4];
            #pragma unroll
            for (int i = 0; i < 8; i++) a[i] = As[k][ty * 8 + i];
            #pragma unroll
            for (int j = 0; j < 4; j++) bv[j] = Bs[k][tx * 4 + j];
            #pragma unroll
            for (int i = 0; i < 8; i++)
                #pragma unroll
                for (int j = 0; j < 4; j++) acc[i][j] += a[i] * bv[j];
        }
        __syncthreads();
    }
    #pragma unroll
    for (int i = 0; i < 8; i++) {
        float ps = 0.f, ps2 = 0.f;
        #pragma unroll
        for (int j = 0; j < 4; j++) { ps += acc[i][j]; ps2 += acc[i][j] * acc[i][j]; }
        #pragma unroll
        for (int o = 1; o < 32; o <<= 1) {
            ps  += __shfl_xor(ps, o, 64);
            ps2 += __shfl_xor(ps2, o, 64);
        }
        float m = ps * (1.f / 128.f);
        float var = ps2 * (1.f / 128.f) - m * m;
        float rstd = rsqrtf(var + 1e-5f);
        int row = m0 + ty * 8 + i;
        int s = row >> 8, t = row & 255;
        int bb = s >> 6, n = s & 63;
        size_t xbase = (((size_t)(bb * 256 + t)) * 64 + n) * CC;
        #pragma unroll
        for (int j = 0; j < 4; j++) {
            int col = tx * 4 + j;
            out[xbase + col] = (acc[i][j] - m) * rstd * g[col] + b[col] + x[xbase + col];
        }
    }
}

extern "C" void kernel_launch(void* const* d_in, const int* in_sizes, int n_in,
                              void* d_out, int out_size, void* d_ws, size_t ws_size,
                              hipStream_t stream) {
    const float* x      = (const float*)d_in[0];
    const float* g1     = (const float*)d_in[1];
    const float* b1     = (const float*)d_in[2];
    const float* W_in   = (const float*)d_in[3];
    const float* conv_w = (const float*)d_in[4];
    const float* conv_b = (const float*)d_in[5];
    const float* Wx     = (const float*)d_in[6];
    const float* Wdt    = (const float*)d_in[7];
    const float* bdt    = (const float*)d_in[8];
    const float* A_log  = (const float*)d_in[9];
    const float* Dvec   = (const float*)d_in[10];
    const float* conv_wb= (const float*)d_in[11];
    const float* conv_bb= (const float*)d_in[12];
    const float* Wxb    = (const float*)d_in[13];
    const float* Wdtb   = (const float*)d_in[14];
    const float* bdtb   = (const float*)d_in[15];
    const float* A_b_log= (const float*)d_in[16];
    const float* D_b    = (const float*)d_in[17];
    const float* W_out  = (const float*)d_in[18];
    const float* g2     = (const float*)d_in[19];
    const float* b2     = (const float*)d_in[20];
    const float* g3     = (const float*)d_in[21];
    const float* b3     = (const float*)d_in[22];
    const float* W1m    = (const float*)d_in[23];
    const float* b1m    = (const float*)d_in[24];
    const float* W2m    = (const float*)d_in[25];
    const float* b2m    = (const float*)d_in[26];

    // Workspace: 64 MiB of bf16 intermediates.
    bf16* ws  = (bf16*)d_ws;
    bf16* XZ  = ws;                    // [ROWS][512] bf16 = 64 MiB
    bf16* H2  = ws;                    // overlay after scans: [ROWS][128] = 16 MiB
    bf16* HID = ws + 8388608UL;        // [ROWS][256] = 32 MiB (ends at 48 MiB)
    float* out = (float*)d_out;        // 8,388,608 fp32 = 32 MiB
    // d_out as bf16 scratch (dead before the real fp32 write of d_out):
    bf16* LN1OUT = (bf16*)d_out;       // [ROWS][128] bf16 = 16 MiB (dead after GEMM1)
    bf16* XDBL_F = (bf16*)d_out;       // [ROWS][40] bf16 (reuses LN1OUT space)
    bf16* XDBL_B = (bf16*)d_out + 2621440UL;

    // 1. LN1 -> d_out scratch (bf16)
    ln1_kernel<<<ROWS / 4, 256, 0, stream>>>(x, g1, b1, LN1OUT);
    // 2. XZ = LN1OUT @ W_in.T  [65536 x 512]
    gemm_kernel<bf16, float, bf16, true, 0><<<dim3(ROWS / 64, 8), 256, 0, stream>>>(
        LN1OUT, CC, W_in, nullptr, XZ, 512, 512, CC);
    // 3. xdbl (fwd/bwd) with fused conv+SiLU A-staging -> d_out scratch
    gemm_conv_kernel<0><<<ROWS / 64, 256, 0, stream>>>(XZ, conv_w, conv_b, Wx, XDBL_F);
    gemm_conv_kernel<1><<<ROWS / 64, 256, 0, stream>>>(XZ, conv_wb, conv_bb, Wxb, XDBL_B);
    // 4. dual scan: backward y_b -> LDS, forward + gate -> z-columns of XZ in place
    scan_dual_kernel<<<SSEQ * 4, 64, 0, stream>>>(XZ, XDBL_F, XDBL_B,
        conv_w, conv_b, Wdt, bdt, A_log, Dvec,
        conv_wb, conv_bb, Wdtb, bdtb, A_b_log, D_b);
    // 5. yproj = gated_sum @ W_out.T, fused LN2 + residual -> d_out fp32 (b,t,n,c)
    gemm_ln2res_kernel<<<ROWS / 64, 256, 0, stream>>>(XZ, W_out, g2, b2, x, out);
    // 6. H2 = LN3(xo) -> ws (XZ dead)
    ln3_kernel<<<ROWS / 4, 256, 0, stream>>>(out, g3, b3, H2);
    // 7. HID = gelu(H2 @ W1m + b1m)  [65536 x 256]
    gemm_kernel<bf16, float, bf16, false, 1><<<dim3(ROWS / 64, 4), 256, 0, stream>>>(
        H2, CC, W1m, b1m, HID, 2 * CC, 2 * CC, CC);
    // 8. d_out += HID @ W2m + b2m
    gemm_kernel<bf16, float, float, false, 2><<<dim3(ROWS / 64, 2), 256, 0, stream>>>(
        HID, 2 * CC, W2m, b2m, out, CC, CC, 2 * CC);
}

// Round 5
// 957.307 us; speedup vs baseline: 1.3363x; 1.3363x over previous
//
#include <hip/hip_runtime.h>
#include <hip/hip_bf16.h>
#include <math.h>

// Problem dims
#define CC 128          // C
#define DI 256          // D_INNER
#define SSEQ 256        // B*N sequences
#define ROWS 65536      // SSEQ*TT

typedef __hip_bfloat16 bf16;
typedef __attribute__((ext_vector_type(8))) short short8;   // 8 bf16 (4 VGPRs) MFMA A/B frag
typedef __attribute__((ext_vector_type(4))) float float4v;  // MFMA C/D frag

__device__ __forceinline__ float to_f(float v) { return v; }
__device__ __forceinline__ float to_f(bf16 v)  { return __bfloat162float(v); }
__device__ __forceinline__ bf16  f2b(float v)  { return __float2bfloat16(v); }

__device__ __forceinline__ float wave_sum(float v) {
    #pragma unroll
    for (int o = 1; o < 64; o <<= 1) v += __shfl_xor(v, o, 64);
    return v;
}
__device__ __forceinline__ float silu_f(float x) { return x / (1.f + __expf(-x)); }
__device__ __forceinline__ float gelu_f(float x) { return 0.5f * x * (1.f + erff(x * 0.70710678118654752f)); }

// ---------------- LN1: x (B,T,N,C) fp32 -> bf16 rows in (s,t) order, s = b*64+n ----------------
__global__ __launch_bounds__(256) void ln1_kernel(const float* __restrict__ x,
                                                  const float* __restrict__ g,
                                                  const float* __restrict__ b,
                                                  bf16* __restrict__ out) {
    int wave = threadIdx.x >> 6, lane = threadIdx.x & 63;
    int r = blockIdx.x * 4 + wave;
    int s = r >> 8, t = r & 255;
    int bb = s >> 6, n = s & 63;
    size_t xbase = (((size_t)(bb * 256 + t)) * 64 + n) * CC;
    float v0 = x[xbase + lane], v1 = x[xbase + lane + 64];
    float s1 = wave_sum(v0 + v1);
    float s2 = wave_sum(v0 * v0 + v1 * v1);
    float m = s1 * (1.f / 128.f);
    float var = s2 * (1.f / 128.f) - m * m;
    float rstd = rsqrtf(var + 1e-5f);
    size_t ob = (size_t)r * CC;
    out[ob + lane]      = f2b((v0 - m) * rstd * g[lane]      + b[lane]);
    out[ob + lane + 64] = f2b((v1 - m) * rstd * g[lane + 64] + b[lane + 64]);
}

// ---------------- LN3: fp32 row-major in -> bf16 out ----------------
__global__ __launch_bounds__(256) void ln3_kernel(const float* __restrict__ in,
                                                  const float* __restrict__ g,
                                                  const float* __restrict__ b,
                                                  bf16* __restrict__ out) {
    int wave = threadIdx.x >> 6, lane = threadIdx.x & 63;
    int r = blockIdx.x * 4 + wave;
    size_t ib = (size_t)r * CC;
    float v0 = in[ib + lane], v1 = in[ib + lane + 64];
    float s1 = wave_sum(v0 + v1);
    float s2 = wave_sum(v0 * v0 + v1 * v1);
    float m = s1 * (1.f / 128.f);
    float var = s2 * (1.f / 128.f) - m * m;
    float rstd = rsqrtf(var + 1e-5f);
    out[ib + lane]      = f2b((v0 - m) * rstd * g[lane]      + b[lane]);
    out[ib + lane + 64] = f2b((v1 - m) * rstd * g[lane + 64] + b[lane + 64]);
}

// ================= MFMA GEMM, 64x64 tile, 256 threads (4 waves) =================
// C[M,N] = A(bf16)[M,K] @ op(B fp32).  BTR=true: B is [N,K] (x @ W.T); false: B is [K,N].
// EPI: 0 = store bf16, 1 = +bias,gelu,store bf16, 2 = +bias, accumulate into fp32 C.
// K = KTILES*32.  A/B staged in LDS as [row][k] bf16 with +8 pad.
// MFMA 16x16x32 frags: A lane holds A[m=lane&15][k=quad*8+j]; B lane holds B[k=quad*8+j][n=lane&15];
// D lane,reg -> row=quad*4+reg, col=lane&15 (guide §3, m89/m91-verified).
template <bool BTR, int EPI, int KTILES>
__global__ __launch_bounds__(256) void mfma_gemm_kernel(const bf16* __restrict__ A, int lda,
                                                        const float* __restrict__ B,
                                                        const float* __restrict__ bias,
                                                        void* __restrict__ Cout, int ldc,
                                                        int N, int K) {
    __shared__ bf16 As[64][40];
    __shared__ bf16 Bs[64][40];
    int tid = threadIdx.x;
    int m0 = blockIdx.x * 64;
    int n0 = blockIdx.y * 64;
    int wv = tid >> 6, lane = tid & 63;
    int lrow = lane & 15, quad = lane >> 4;
    int lk = quad * 8;
    float4v acc[4] = {};
    #pragma unroll
    for (int kt = 0; kt < KTILES; kt++) {
        int k0 = kt * 32;
        // ---- A stage: 64 rows x 32 k, 8 bf16 per thread ----
        {
            int m = tid >> 2, part = tid & 3;
            uint4 v = *(const uint4*)(A + (size_t)(m0 + m) * lda + k0 + part * 8);
            *(uint4*)&As[m][part * 8] = v;
        }
        // ---- B stage (fp32 -> bf16): LDS layout Bs[n][k] ----
        if (BTR) {
            int n = tid >> 2, part = tid & 3;
            const float* src = B + (size_t)(n0 + n) * K + k0 + part * 8;
            bf16 tmp[8];
            #pragma unroll
            for (int j = 0; j < 8; j++) tmp[j] = f2b(src[j]);
            *(uint4*)&Bs[n][part * 8] = *(uint4*)tmp;
        } else {
            int kk = tid >> 3, nf = (tid & 7) * 8;
            const float* src = B + (size_t)(k0 + kk) * N + n0 + nf;
            #pragma unroll
            for (int j = 0; j < 8; j++) Bs[nf + j][kk] = f2b(src[j]);
        }
        __syncthreads();
        short8 a = *(const short8*)&As[wv * 16 + lrow][lk];
        #pragma unroll
        for (int jt = 0; jt < 4; jt++) {
            short8 bfr = *(const short8*)&Bs[jt * 16 + lrow][lk];
            acc[jt] = __builtin_amdgcn_mfma_f32_16x16x32_bf16(a, bfr, acc[jt], 0, 0, 0);
        }
        __syncthreads();
    }
    // ---- epilogue (pointwise) ----
    #pragma unroll
    for (int jt = 0; jt < 4; jt++) {
        int col = n0 + jt * 16 + lrow;
        float bs = (EPI >= 1) ? bias[col] : 0.f;
        #pragma unroll
        for (int r = 0; r < 4; r++) {
            int row = m0 + wv * 16 + quad * 4 + r;
            float v = acc[jt][r] + bs;
            if (EPI == 1) v = gelu_f(v);
            if (EPI == 2) {
                float* Cf = (float*)Cout;
                Cf[(size_t)row * ldc + col] += v;
            } else {
                bf16* Cb = (bf16*)Cout;
                Cb[(size_t)row * ldc + col] = f2b(v);
            }
        }
    }
}

// ======== MFMA W_out GEMM (64x128 tile) with fused LN2 + residual epilogue ========
// A = gated sum in z-columns of xz (bf16, lda 512, +256 offset). B = W_out [128][256] fp32 (BTR).
// Each wave: 16 rows x 128 cols -> row LN stats via 16-lane quad shuffle reduce.
__global__ __launch_bounds__(256) void mfma_ln2res_kernel(const bf16* __restrict__ xz,
                                                          const float* __restrict__ Wout,
                                                          const float* __restrict__ g,
                                                          const float* __restrict__ b,
                                                          const float* __restrict__ x,
                                                          float* __restrict__ out) {
    __shared__ bf16 As[64][40];
    __shared__ bf16 Bs[128][40];
    int tid = threadIdx.x;
    int m0 = blockIdx.x * 64;
    int wv = tid >> 6, lane = tid & 63;
    int lrow = lane & 15, quad = lane >> 4;
    int lk = quad * 8;
    float4v acc[8] = {};
    #pragma unroll
    for (int kt = 0; kt < 8; kt++) {          // K = 256
        int k0 = kt * 32;
        {
            int m = tid >> 2, part = tid & 3;
            uint4 v = *(const uint4*)(xz + (size_t)(m0 + m) * 512 + 256 + k0 + part * 8);
            *(uint4*)&As[m][part * 8] = v;
        }
        #pragma unroll
        for (int it = 0; it < 2; it++) {      // 128 n x 4 parts = 512 slots
            int idx = tid + it * 256;
            int n = idx >> 2, part = idx & 3;
            const float* src = Wout + (size_t)n * 256 + k0 + part * 8;
            bf16 tmp[8];
            #pragma unroll
            for (int j = 0; j < 8; j++) tmp[j] = f2b(src[j]);
            *(uint4*)&Bs[n][part * 8] = *(uint4*)tmp;
        }
        __syncthreads();
        short8 a = *(const short8*)&As[wv * 16 + lrow][lk];
        #pragma unroll
        for (int jt = 0; jt < 8; jt++) {
            short8 bfr = *(const short8*)&Bs[jt * 16 + lrow][lk];
            acc[jt] = __builtin_amdgcn_mfma_f32_16x16x32_bf16(a, bfr, acc[jt], 0, 0, 0);
        }
        __syncthreads();
    }
    // ---- LN2 + residual epilogue ----
    // Row (quad*4+r) of this wave spans jt=0..7 tiles x 16 lanes of this quad.
    #pragma unroll
    for (int r = 0; r < 4; r++) {
        float ps = 0.f, ps2 = 0.f;
        #pragma unroll
        for (int jt = 0; jt < 8; jt++) { float v = acc[jt][r]; ps += v; ps2 += v * v; }
        #pragma unroll
        for (int o = 1; o < 16; o <<= 1) {    // reduce across the 16 lanes of the quad
            ps  += __shfl_xor(ps, o, 64);
            ps2 += __shfl_xor(ps2, o, 64);
        }
        float m = ps * (1.f / 128.f);
        float var = ps2 * (1.f / 128.f) - m * m;
        float rstd = rsqrtf(var + 1e-5f);
        int row = m0 + wv * 16 + quad * 4 + r;
        int s = row >> 8, t = row & 255;
        int bb = s >> 6, n = s & 63;
        size_t xbase = (((size_t)(bb * 256 + t)) * 64 + n) * CC;
        #pragma unroll
        for (int jt = 0; jt < 8; jt++) {
            int col = jt * 16 + lrow;
            out[xbase + col] = (acc[jt][r] - m) * rstd * g[col] + b[col] + x[xbase + col];
        }
    }
}

// ---------------- xdbl GEMM with fused causal conv + SiLU A-staging (VALU, N=40) ----------------
template <int DIR>
__global__ __launch_bounds__(256) void gemm_conv_kernel(const bf16* __restrict__ xz,
                                                        const float* __restrict__ cw,
                                                        const float* __restrict__ cb,
                                                        const float* __restrict__ B,
                                                        bf16* __restrict__ C) {
    __shared__ float As[16][65];
    __shared__ float Bs[16][65];
    int tid = threadIdx.x;
    int m0 = blockIdx.x * 64;
    int tx = tid & 15, ty = tid >> 4;
    float acc[4][4] = {};
    for (int k0 = 0; k0 < 256; k0 += 16) {
        #pragma unroll
        for (int r = 0; r < 4; r++) {
            int idx = tid + r * 256;
            int m = idx >> 4, kk = idx & 15;
            int row = m0 + m;
            int t = row & 255, s = row >> 8;
            int d = k0 + kk;
            float a = cb[d];
            #pragma unroll
            for (int j = 0; j < 4; j++) {
                int tj = t - 3 + j;
                if (tj >= 0) {
                    int src = DIR ? (255 - tj) : tj;
                    a += cw[d * 4 + j] * to_f(xz[(size_t)(s * 256 + src) * 512 + d]);
                }
            }
            As[kk][m] = silu_f(a);
        }
        #pragma unroll
        for (int r = 0; r < 4; r++) {
            int idx = tid + r * 256;
            int n = idx >> 4, kk = idx & 15;
            Bs[kk][n] = (n < 40) ? B[(size_t)n * 256 + k0 + kk] : 0.f;
        }
        __syncthreads();
        #pragma unroll
        for (int k = 0; k < 16; k++) {
            float a[4], bv[4];
            #pragma unroll
            for (int i = 0; i < 4; i++) a[i] = As[k][ty * 4 + i];
            #pragma unroll
            for (int j = 0; j < 4; j++) bv[j] = Bs[k][tx * 4 + j];
            #pragma unroll
            for (int i = 0; i < 4; i++)
                #pragma unroll
                for (int j = 0; j < 4; j++) acc[i][j] += a[i] * bv[j];
        }
        __syncthreads();
    }
    #pragma unroll
    for (int i = 0; i < 4; i++) {
        int row = m0 + ty * 4 + i;
        #pragma unroll
        for (int j = 0; j < 4; j++) {
            int col = tx * 4 + j;
            if (col < 40) C[(size_t)row * 40 + col] = f2b(acc[i][j]);
        }
    }
}

// ---------------- Dual selective scan (unchanged from round 4) ----------------
__global__ __launch_bounds__(64) void scan_dual_kernel(bf16* __restrict__ xz,
        const bf16* __restrict__ xdbl_f, const bf16* __restrict__ xdbl_b,
        const float* __restrict__ cw_f, const float* __restrict__ cb_f,
        const float* __restrict__ Wdt_f, const float* __restrict__ bdt_f,
        const float* __restrict__ Alog_f, const float* __restrict__ D_f,
        const float* __restrict__ cw_b, const float* __restrict__ cb_b,
        const float* __restrict__ Wdt_b, const float* __restrict__ bdt_b,
        const float* __restrict__ Alog_b, const float* __restrict__ D_b) {
    __shared__ bf16 ybuf[256 * 64];   // y_b (ungated) indexed by ORIGINAL time
    __shared__ float sm[40];
    int tid = threadIdx.x;
    int s = blockIdx.x >> 2, q = blockIdx.x & 3;
    int d = q * 64 + tid;

    // ---- Phase A: backward ----
    {
        float A[16], wdt[8];
        #pragma unroll
        for (int n = 0; n < 16; n++) A[n] = -__expf(Alog_b[d * 16 + n]);
        #pragma unroll
        for (int r = 0; r < 8; r++) wdt[r] = Wdt_b[d * 8 + r];
        float bd = bdt_b[d], Dd = D_b[d];
        float c0 = cw_b[d * 4], c1 = cw_b[d * 4 + 1], c2 = cw_b[d * 4 + 2], c3 = cw_b[d * 4 + 3];
        float cb = cb_b[d];
        float h[16];
        #pragma unroll
        for (int n = 0; n < 16; n++) h[n] = 0.f;
        float w0 = 0.f, w1 = 0.f, w2 = 0.f, w3 = 0.f;
        for (int t = 0; t < 256; t++) {
            int orig = 255 - t;
            float xc = to_f(xz[(size_t)(s * 256 + orig) * 512 + d]);
            __syncthreads();
            if (tid < 40) sm[tid] = to_f(xdbl_b[(size_t)(s * 256 + t) * 40 + tid]);
            __syncthreads();
            w0 = w1; w1 = w2; w2 = w3; w3 = xc;
            float u = silu_f(cb + c0 * w0 + c1 * w1 + c2 * w2 + c3 * w3);
            float dtr = bd;
            #pragma unroll
            for (int r = 0; r < 8; r++) dtr += sm[r] * wdt[r];
            float dt = (dtr > 20.f) ? dtr : log1pf(__expf(dtr));
            float du = dt * u, y = 0.f;
            #pragma unroll
            for (int n = 0; n < 16; n++) {
                float dA = __expf(dt * A[n]);
                h[n] = dA * h[n] + du * sm[8 + n];
                y += h[n] * sm[24 + n];
            }
            y += u * Dd;
            ybuf[orig * 64 + tid] = f2b(y);
        }
    }
    __syncthreads();
    // ---- Phase B: forward + gate, write into z columns ----
    {
        float A[16], wdt[8];
        #pragma unroll
        for (int n = 0; n < 16; n++) A[n] = -__expf(Alog_f[d * 16 + n]);
        #pragma unroll
        for (int r = 0; r < 8; r++) wdt[r] = Wdt_f[d * 8 + r];
        float bd = bdt_f[d], Dd = D_f[d];
        float c0 = cw_f[d * 4], c1 = cw_f[d * 4 + 1], c2 = cw_f[d * 4 + 2], c3 = cw_f[d * 4 + 3];
        float cb = cb_f[d];
        float h[16];
        #pragma unroll
        for (int n = 0; n < 16; n++) h[n] = 0.f;
        float w0 = 0.f, w1 = 0.f, w2 = 0.f, w3 = 0.f;
        for (int t = 0; t < 256; t++) {
            float xc = to_f(xz[(size_t)(s * 256 + t) * 512 + d]);
            __syncthreads();
            if (tid < 40) sm[tid] = to_f(xdbl_f[(size_t)(s * 256 + t) * 40 + tid]);
            __syncthreads();
            w0 = w1; w1 = w2; w2 = w3; w3 = xc;
            float u = silu_f(cb + c0 * w0 + c1 * w1 + c2 * w2 + c3 * w3);
            float dtr = bd;
            #pragma unroll
            for (int r = 0; r < 8; r++) dtr += sm[r] * wdt[r];
            float dt = (dtr > 20.f) ? dtr : log1pf(__expf(dtr));
            float du = dt * u, y = 0.f;
            #pragma unroll
            for (int n = 0; n < 16; n++) {
                float dA = __expf(dt * A[n]);
                h[n] = dA * h[n] + du * sm[8 + n];
                y += h[n] * sm[24 + n];
            }
            y += u * Dd;
            float yb = to_f(ybuf[t * 64 + tid]);
            size_t za = (size_t)(s * 256 + t) * 512 + 256 + d;
            float z = to_f(xz[za]);
            xz[za] = f2b((y + yb) * silu_f(z));
        }
    }
}

extern "C" void kernel_launch(void* const* d_in, const int* in_sizes, int n_in,
                              void* d_out, int out_size, void* d_ws, size_t ws_size,
                              hipStream_t stream) {
    const float* x      = (const float*)d_in[0];
    const float* g1     = (const float*)d_in[1];
    const float* b1     = (const float*)d_in[2];
    const float* W_in   = (const float*)d_in[3];
    const float* conv_w = (const float*)d_in[4];
    const float* conv_b = (const float*)d_in[5];
    const float* Wx     = (const float*)d_in[6];
    const float* Wdt    = (const float*)d_in[7];
    const float* bdt    = (const float*)d_in[8];
    const float* A_log  = (const float*)d_in[9];
    const float* Dvec   = (const float*)d_in[10];
    const float* conv_wb= (const float*)d_in[11];
    const float* conv_bb= (const float*)d_in[12];
    const float* Wxb    = (const float*)d_in[13];
    const float* Wdtb   = (const float*)d_in[14];
    const float* bdtb   = (const float*)d_in[15];
    const float* A_b_log= (const float*)d_in[16];
    const float* D_b    = (const float*)d_in[17];
    const float* W_out  = (const float*)d_in[18];
    const float* g2     = (const float*)d_in[19];
    const float* b2     = (const float*)d_in[20];
    const float* g3     = (const float*)d_in[21];
    const float* b3     = (const float*)d_in[22];
    const float* W1m    = (const float*)d_in[23];
    const float* b1m    = (const float*)d_in[24];
    const float* W2m    = (const float*)d_in[25];
    const float* b2m    = (const float*)d_in[26];

    // Workspace: 64 MiB of bf16 intermediates.
    bf16* ws  = (bf16*)d_ws;
    bf16* XZ  = ws;                    // [ROWS][512] bf16 = 64 MiB
    bf16* H2  = ws;                    // overlay after scans: [ROWS][128] = 16 MiB
    bf16* HID = ws + 8388608UL;        // [ROWS][256] = 32 MiB (ends at 48 MiB)
    float* out = (float*)d_out;        // 8,388,608 fp32 = 32 MiB
    // d_out as bf16 scratch (dead before the real fp32 write of d_out):
    bf16* LN1OUT = (bf16*)d_out;       // [ROWS][128] bf16 = 16 MiB (dead after GEMM2)
    bf16* XDBL_F = (bf16*)d_out;       // [ROWS][40] bf16 (reuses LN1OUT space)
    bf16* XDBL_B = (bf16*)d_out + 2621440UL;

    // 1. LN1 -> d_out scratch (bf16)
    ln1_kernel<<<ROWS / 4, 256, 0, stream>>>(x, g1, b1, LN1OUT);
    // 2. XZ = LN1OUT @ W_in.T  [65536 x 512]  (MFMA)
    mfma_gemm_kernel<true, 0, 4><<<dim3(ROWS / 64, 8), 256, 0, stream>>>(
        LN1OUT, CC, W_in, nullptr, XZ, 512, 512, CC);
    // 3. xdbl (fwd/bwd) with fused conv+SiLU A-staging -> d_out scratch
    gemm_conv_kernel<0><<<ROWS / 64, 256, 0, stream>>>(XZ, conv_w, conv_b, Wx, XDBL_F);
    gemm_conv_kernel<1><<<ROWS / 64, 256, 0, stream>>>(XZ, conv_wb, conv_bb, Wxb, XDBL_B);
    // 4. dual scan: backward y_b -> LDS, forward + gate -> z-columns of XZ in place
    scan_dual_kernel<<<SSEQ * 4, 64, 0, stream>>>(XZ, XDBL_F, XDBL_B,
        conv_w, conv_b, Wdt, bdt, A_log, Dvec,
        conv_wb, conv_bb, Wdtb, bdtb, A_b_log, D_b);
    // 5. yproj = gated_sum @ W_out.T, fused LN2 + residual -> d_out fp32 (MFMA)
    mfma_ln2res_kernel<<<ROWS / 64, 256, 0, stream>>>(XZ, W_out, g2, b2, x, out);
    // 6. H2 = LN3(xo) -> ws (XZ dead)
    ln3_kernel<<<ROWS / 4, 256, 0, stream>>>(out, g3, b3, H2);
    // 7. HID = gelu(H2 @ W1m + b1m)  [65536 x 256]  (MFMA)
    mfma_gemm_kernel<false, 1, 4><<<dim3(ROWS / 64, 4), 256, 0, stream>>>(
        H2, CC, W1m, b1m, HID, 2 * CC, 2 * CC, CC);
    // 8. d_out += HID @ W2m + b2m  (MFMA, fp32 accumulate)
    mfma_gemm_kernel<false, 2, 8><<<dim3(ROWS / 64, 2), 256, 0, stream>>>(
        HID, 2 * CC, W2m, b2m, out, CC, CC, 2 * CC);
}